// Round 1
// baseline (280.977 us; speedup 1.0000x reference)
//
#include <hip/hip_runtime.h>

#define D 256

// ---------------- CSR build ----------------

__global__ void zero_int(int* __restrict__ p, int n) {
    int i = blockIdx.x * blockDim.x + threadIdx.x;
    if (i < n) p[i] = 0;
}

__global__ void degree_kernel(const int* __restrict__ dst, int* __restrict__ deg, int E) {
    int e = blockIdx.x * blockDim.x + threadIdx.x;
    if (e < E) atomicAdd(&deg[dst[e]], 1);
}

// single-block exclusive scan over n<=16384 elements (n=10000 here)
__global__ __launch_bounds__(1024) void scan_kernel(const int* __restrict__ deg,
                                                    int* __restrict__ offsets,
                                                    int* __restrict__ cursor, int n) {
    const int CHUNK = 16;
    __shared__ int s[1024];
    int t = threadIdx.x;
    int base_idx = t * CHUNK;
    int vals[CHUNK];
    int local = 0;
#pragma unroll
    for (int i = 0; i < CHUNK; ++i) {
        int idx = base_idx + i;
        int v = (idx < n) ? deg[idx] : 0;
        vals[i] = v;
        local += v;
    }
    s[t] = local;
    __syncthreads();
    // Hillis-Steele inclusive scan over 1024 partials
    for (int off = 1; off < 1024; off <<= 1) {
        int v = (t >= off) ? s[t - off] : 0;
        __syncthreads();
        s[t] += v;
        __syncthreads();
    }
    int run = s[t] - local;  // exclusive base for this thread's chunk
#pragma unroll
    for (int i = 0; i < CHUNK; ++i) {
        int idx = base_idx + i;
        if (idx < n) {
            offsets[idx] = run;
            cursor[idx]  = run;
            run += vals[i];
        }
    }
    if (t == 1023) offsets[n] = s[1023];
}

__global__ void bucket_kernel(const int* __restrict__ src, const int* __restrict__ dst,
                              int* __restrict__ cursor, int* __restrict__ csr, int E) {
    int e = blockIdx.x * blockDim.x + threadIdx.x;
    if (e < E) {
        int d = dst[e];
        int pos = atomicAdd(&cursor[d], 1);
        csr[pos] = src[e];
    }
}

// ---------------- aggregation: one wave per node ----------------

__global__ __launch_bounds__(256) void agg_kernel(const float* __restrict__ x,
                                                  const int* __restrict__ csr,
                                                  const int* __restrict__ offsets,
                                                  float* __restrict__ agg, int M) {
    int node = (blockIdx.x * 256 + threadIdx.x) >> 6;
    int lane = threadIdx.x & 63;
    if (node >= M) return;
    int start = offsets[node];
    int end   = offsets[node + 1];
    float4 acc = {0.f, 0.f, 0.f, 0.f};
    for (int e = start; e < end; ++e) {
        int s = csr[e];
        const float4 v = *(const float4*)&x[(long)s * D + lane * 4];
        acc.x += v.x; acc.y += v.y; acc.z += v.z; acc.w += v.w;
    }
    int cnt = end - start;
    float sc = 1.0f / (float)(cnt > 0 ? cnt : 1);
    acc.x *= sc; acc.y *= sc; acc.z *= sc; acc.w *= sc;
    *(float4*)&agg[(long)node * D + lane * 4] = acc;
}

// ---------------- tiled fp32 GEMM: C = relu(A1*B1^T (+ A2*B2^T) + bias) ----------------
// A: [M,K] row-major, B: [N,K] row-major (torch Linear layout), C: [M,N]

template <int BM, int BN, int BK, int TM, int TN, bool RELU, bool DUAL>
__global__ __launch_bounds__((BM / TM) * (BN / TN))
void gemm_bias_relu(const float* __restrict__ A1, const float* __restrict__ B1,
                    const float* __restrict__ A2, const float* __restrict__ B2,
                    const float* __restrict__ bias, float* __restrict__ C,
                    int M, int N, int K) {
    static_assert(TM == 4 && TN == 4, "epilogue assumes 4x4");
    static_assert(BM == BN, "loader assumes BM==BN");
    constexpr int THREADS = (BM / TM) * (BN / TN);
    constexpr int TX = BN / TN;
    static_assert(THREADS == BM * (BK / 4), "one float4 per thread per tile");
    __shared__ float As[BK][BM + 4];  // +4 floats: row stride 272B (16B-aligned), conflict-free-ish
    __shared__ float Bs[BK][BN + 4];

    const int tid = threadIdx.x;
    const int tx = tid % TX;
    const int ty = tid / TX;
    const int m0 = blockIdx.x * BM;
    const int n0 = blockIdx.y * BN;

    // loader mapping: thread -> (row, 4-wide col chunk)
    const int l_r = tid / (BK / 4);
    const int l_c = (tid % (BK / 4)) * 4;

    float acc[TM][TN] = {};

    const int npass = DUAL ? 2 : 1;
    for (int pass = 0; pass < npass; ++pass) {
        const float* __restrict__ A = (DUAL && pass) ? A2 : A1;
        const float* __restrict__ B = (DUAL && pass) ? B2 : B1;
        for (int kk = 0; kk < K; kk += BK) {
            // stage A tile (guard M edge with zeros)
            {
                float4 v = {0.f, 0.f, 0.f, 0.f};
                int gm = m0 + l_r;
                if (gm < M) v = *(const float4*)&A[(long)gm * K + kk + l_c];
                As[l_c + 0][l_r] = v.x;
                As[l_c + 1][l_r] = v.y;
                As[l_c + 2][l_r] = v.z;
                As[l_c + 3][l_r] = v.w;
            }
            // stage B tile (N % BN == 0 guaranteed by launch config)
            {
                float4 v = *(const float4*)&B[(long)(n0 + l_r) * K + kk + l_c];
                Bs[l_c + 0][l_r] = v.x;
                Bs[l_c + 1][l_r] = v.y;
                Bs[l_c + 2][l_r] = v.z;
                Bs[l_c + 3][l_r] = v.w;
            }
            __syncthreads();
#pragma unroll
            for (int k = 0; k < BK; ++k) {
                float4 a4 = *(const float4*)&As[k][ty * TM];
                float4 b4 = *(const float4*)&Bs[k][tx * TN];
                float a[4] = {a4.x, a4.y, a4.z, a4.w};
                float b[4] = {b4.x, b4.y, b4.z, b4.w};
#pragma unroll
                for (int i = 0; i < TM; ++i)
#pragma unroll
                    for (int j = 0; j < TN; ++j) acc[i][j] = fmaf(a[i], b[j], acc[i][j]);
            }
            __syncthreads();
        }
    }

#pragma unroll
    for (int i = 0; i < TM; ++i) {
        int gm = m0 + ty * TM + i;
        if (gm >= M) continue;
        float4 o;
        float* po = (float*)&o;
#pragma unroll
        for (int j = 0; j < TN; ++j) {
            float v = acc[i][j] + bias[n0 + tx * TN + j];
            if (RELU) v = fmaxf(v, 0.f);
            po[j] = v;
        }
        *(float4*)&C[(long)gm * N + n0 + tx * TN] = o;
    }
}

// ---------------- fused tail: h3[64] -> relu(W2)->32 -> W3 -> 3 ----------------

__global__ __launch_bounds__(256) void tail_kernel(const float* __restrict__ h3,
                                                   const float* __restrict__ W2,
                                                   const float* __restrict__ b2,
                                                   const float* __restrict__ W3,
                                                   const float* __restrict__ b3,
                                                   float* __restrict__ out, int M) {
    __shared__ float sW2[32 * 64];
    __shared__ float sW3[3 * 32];
    __shared__ float sb2[32];
    __shared__ float sb3[3];
    int t = threadIdx.x;
    for (int i = t; i < 32 * 64; i += 256) sW2[i] = W2[i];
    if (t < 96) sW3[t] = W3[t];
    if (t < 32) sb2[t] = b2[t];
    if (t < 3) sb3[t] = b3[t];
    __syncthreads();
    int m = blockIdx.x * 256 + t;
    if (m >= M) return;
    float r[64];
    const float4* hp = (const float4*)&h3[(long)m * 64];
#pragma unroll
    for (int i = 0; i < 16; ++i) {
        float4 v = hp[i];
        r[4 * i + 0] = v.x; r[4 * i + 1] = v.y; r[4 * i + 2] = v.z; r[4 * i + 3] = v.w;
    }
    float h4[32];
#pragma unroll
    for (int j = 0; j < 32; ++j) {
        float a = sb2[j];
#pragma unroll
        for (int k = 0; k < 64; ++k) a = fmaf(r[k], sW2[j * 64 + k], a);
        h4[j] = fmaxf(a, 0.f);
    }
#pragma unroll
    for (int j = 0; j < 3; ++j) {
        float a = sb3[j];
#pragma unroll
        for (int k = 0; k < 32; ++k) a = fmaf(h4[k], sW3[j * 32 + k], a);
        out[(long)m * 3 + j] = a;
    }
}

// ---------------- launch ----------------

extern "C" void kernel_launch(void* const* d_in, const int* in_sizes, int n_in,
                              void* d_out, int out_size, void* d_ws, size_t ws_size,
                              hipStream_t stream) {
    const float* x   = (const float*)d_in[0];
    const int*   ei  = (const int*)d_in[1];
    const float* W_l = (const float*)d_in[2];
    const float* b_l = (const float*)d_in[3];
    const float* W_r = (const float*)d_in[4];
    const float* Wa  = (const float*)d_in[5];
    const float* ba  = (const float*)d_in[6];
    const float* W1  = (const float*)d_in[7];
    const float* b1  = (const float*)d_in[8];
    const float* W2  = (const float*)d_in[9];
    const float* b2  = (const float*)d_in[10];
    const float* W3  = (const float*)d_in[11];
    const float* b3  = (const float*)d_in[12];
    float* out = (float*)d_out;

    const int M = in_sizes[0] / D;   // 10000
    const int E = in_sizes[1] / 2;   // 320000
    const int* src = ei;
    const int* dst = ei + E;

    // workspace carve (all 16B aligned)
    char* ws = (char*)d_ws;
    int* deg     = (int*)ws;            ws += (size_t)M * 4;          // 40000 (mult of 16)
    int* offsets = (int*)ws;            ws += (size_t)(M + 8) * 4;    // 40032
    int* cursor  = (int*)ws;            ws += (size_t)M * 4;
    int* csr     = (int*)ws;            ws += (size_t)E * 4;
    float* agg   = (float*)ws;          ws += (size_t)M * 256 * 4;
    float* h1    = (float*)ws;          ws += (size_t)M * 256 * 4;
    float* h2    = (float*)ws;          ws += (size_t)M * 128 * 4;
    float* h3    = (float*)ws;          ws += (size_t)M * 64 * 4;

    zero_int<<<(M + 255) / 256, 256, 0, stream>>>(deg, M);
    degree_kernel<<<(E + 255) / 256, 256, 0, stream>>>(dst, deg, E);
    scan_kernel<<<1, 1024, 0, stream>>>(deg, offsets, cursor, M);
    bucket_kernel<<<(E + 255) / 256, 256, 0, stream>>>(src, dst, cursor, csr, E);
    agg_kernel<<<(M + 3) / 4, 256, 0, stream>>>(x, csr, offsets, agg, M);

    // layer 1: h1 = relu(agg@W_l^T + x@W_r^T + b_l)   [M,256]
    dim3 g1((M + 63) / 64, 256 / 64);
    gemm_bias_relu<64, 64, 16, 4, 4, true, true><<<g1, 256, 0, stream>>>(
        agg, W_l, x, W_r, b_l, h1, M, 256, 256);
    // layer 2: h2 = relu(h1@Wa^T + ba)  [M,128]
    dim3 g2((M + 63) / 64, 128 / 64);
    gemm_bias_relu<64, 64, 16, 4, 4, true, false><<<g2, 256, 0, stream>>>(
        h1, Wa, nullptr, nullptr, ba, h2, M, 128, 256);
    // layer 3: h3 = relu(h2@W1^T + b1)  [M,64]
    dim3 g3((M + 63) / 64, 1);
    gemm_bias_relu<64, 64, 16, 4, 4, true, false><<<g3, 256, 0, stream>>>(
        h2, W1, nullptr, nullptr, b1, h3, M, 64, 128);
    // layers 4+5 fused
    tail_kernel<<<(M + 255) / 256, 256, 0, stream>>>(h3, W2, b2, W3, b3, out, M);
}